// Round 12
// baseline (106.157 us; speedup 1.0000x reference)
//
#include <hip/hip_runtime.h>
#include <stdint.h>

// pairs_of_pairs: fused [concat -> conv1x1+relu x3]
// B=32, C=64, S=64, CC=128, OC=256. 2016 rows of 64 positions.
// R11 = R10 + {launch_bounds(512,1) -> VGPR cap 256, full kk unroll,
// build/layer-0 overlap}. Rationale: 1 block/CU is this structure's stable
// equilibrium (R6/R7 falsified smaller-block co-residency), so each wave owns
// 256 VGPR; R10 used only 108 with unroll-2 -> latency-bound with idle regs.
// Full unroll + reg headroom lets the compiler pipeline the 16 A-loads and
// 64 ds_reads per layer. Build: chunks 0,1 built first; x-chunk loads issued
// into regs, kk0-3 (chunks 0,1 only) run under them, c2 written, bar, kk4-7.
// Kept from R10: 2 rows/block (b0,b0+16), 512 thr, 8 waves x 32o x 128pos,
// xaddr chunk swizzle, rolled chunk aliased from chunk2, direct build,
// full-64KB bounce epilogue.

typedef __attribute__((ext_vector_type(8))) __bf16 bf16x8;
typedef __attribute__((ext_vector_type(4))) float f32x4;
typedef __attribute__((ext_vector_type(4))) unsigned short u16x4;
typedef __attribute__((ext_vector_type(8))) unsigned short u16x8;

__device__ __forceinline__ unsigned short f2bf(float f) {
  unsigned int u = __builtin_bit_cast(unsigned int, f);
  u += 0x7FFFu + ((u >> 16) & 1u);
  return (unsigned short)(u >> 16);
}

// X: 4 chunk regions of [128 pos][64 ch] bf16 (8192 elems each).
// Within chunk: 16B-slot = pos*8 + ((c6/8) ^ (pos&7)) -> max 2-way (free).
__device__ __forceinline__ int xaddr(int pos, int c) {
  int slot = (pos << 3) + ((((c & 63) >> 3) ^ pos) & 7);
  return ((c >> 6) << 13) + (slot << 3) + (c & 7);
}

__global__ void wconv_kernel(const float* __restrict__ W1, const float* __restrict__ W2,
                             const float* __restrict__ W3, unsigned short* __restrict__ wb) {
  int i = (blockIdx.x * 256 + threadIdx.x) * 4;  // grid 64 -> 65536 per layer
  const float* Ws[3] = {W1, W2, W3};
#pragma unroll
  for (int L = 0; L < 3; ++L) {
    f32x4 a = *(const f32x4*)(Ws[L] + i);
    u16x4 p;
#pragma unroll
    for (int v = 0; v < 4; ++v) p[v] = f2bf(a[v]);
    *(u16x4*)(wb + L * 65536 + i) = p;
  }
}

__global__ __launch_bounds__(512, 1)
void fused_kernel(const float* __restrict__ x, const float* __restrict__ xc,
                  const unsigned short* __restrict__ wb,
                  const float* __restrict__ b1, const float* __restrict__ b2,
                  const float* __restrict__ b3, float* __restrict__ out) {
  __shared__ __align__(16) unsigned char lraw[65536];
  unsigned short* X = (unsigned short*)lraw;   // 64KB, 4 chunk regions
  float* bounce = (float*)lraw;                // full 64KB epilogue reuse

  const int r = blockIdx.x;       // 0..1007
  const int b0 = r / 63;          // 0..15 ; row1 uses b0+16
  const int dd = r % 63;
  const int d = dd + 1;
  const int tid = threadIdx.x;    // 0..511
  const int lane = tid & 63;
  const int g16 = lane >> 4;
  const int l16 = lane & 15;
  const int wv = tid >> 6;        // wave 0..7

  const int p = tid & 63;         // build: position owned by this thread
  const int c0 = (tid >> 6) << 3; // build: c-octet 0,8,...,56

  // ---- issue x-chunk loads FIRST (latency hidden under build + kk0-3) ----
  float xreg[2][8];
#pragma unroll
  for (int rr = 0; rr < 2; ++rr)
#pragma unroll
    for (int j = 0; j < 8; ++j)
      xreg[rr][j] = x[((b0 + 16 * rr) * 64 + c0 + j) * 64 + p];

  // ---- build chunks 0,1 (xc) for both rows: direct global->LDS ----
#pragma unroll
  for (int cr = 0; cr < 4; ++cr) {
    const int rr = cr >> 1;
    const int ck = cr & 1;
    const int b = b0 + 16 * rr;
    u16x8 v;
#pragma unroll
    for (int j = 0; j < 8; ++j)
      v[j] = f2bf(xc[(((b * 128 + ck * 64 + c0 + j) * 63) + dd) * 64 + p]);
    *(u16x8*)&X[xaddr(rr * 64 + p, ck * 64 + c0)] = v;
  }
  __syncthreads();  // chunks 0,1 ready

  // ---------------- 3 fused conv1x1+relu layers ----------------
  for (int layer = 0; layer < 3; ++layer) {
    const unsigned short* wl = wb + layer * 65536;
    const float* bias = (layer == 0) ? b1 : (layer == 1) ? b2 : b3;
    const bool al3 = (layer == 0);     // layer 0: k in [192,256) aliases chunk2 shifted

    f32x4 acc[2][8] = {};              // [mf][nf], wave tile = 32 o x 128 pos
    const int ow = wv * 32;

    const int kkmid = al3 ? 4 : 8;     // layer 0: kk 0-3 before c2 is written

#pragma unroll
    for (int kk = 0; kk < 8; ++kk) {   // FULL unroll; branches fold
      if (al3 && kk == 4) {
        // write x-chunk (c2) from regs, then barrier; kk0-3 used chunks 0,1 only
#pragma unroll
        for (int rr = 0; rr < 2; ++rr) {
          u16x8 v;
#pragma unroll
          for (int j = 0; j < 8; ++j) v[j] = f2bf(xreg[rr][j]);
          *(u16x8*)&X[xaddr(rr * 64 + p, 128 + c0)] = v;
        }
        __syncthreads();               // c2 ready for kk 4-7
      }
      int kb = kk * 32 + g16 * 8;      // this lane-group's k-base
      bool a3 = al3 && (kk >= 6);
      int cc = a3 ? (128 + (kb & 63)) : kb;  // rolled -> chunk2 region
      bf16x8 afr[2];
#pragma unroll
      for (int mf = 0; mf < 2; ++mf)
        afr[mf] = __builtin_bit_cast(
            bf16x8, *(const u16x8*)(wl + (ow + mf * 16 + l16) * 256 + kb));
      bf16x8 bfr[4];
#pragma unroll
      for (int nf = 0; nf < 4; ++nf) { // row0 positions 0..63
        int i = nf * 16 + l16;
        int ie = a3 ? ((i - d) & 63) : i;
        bfr[nf] = __builtin_bit_cast(bf16x8, *(const u16x8*)&X[xaddr(ie, cc)]);
      }
#pragma unroll
      for (int mf = 0; mf < 2; ++mf)
#pragma unroll
        for (int nf = 0; nf < 4; ++nf)
          acc[mf][nf] = __builtin_amdgcn_mfma_f32_16x16x32_bf16(afr[mf], bfr[nf], acc[mf][nf], 0, 0, 0);
#pragma unroll
      for (int nf = 0; nf < 4; ++nf) { // row1 positions 64..127
        int i = nf * 16 + l16;
        int ie = 64 + (a3 ? ((i - d) & 63) : i);
        bfr[nf] = __builtin_bit_cast(bf16x8, *(const u16x8*)&X[xaddr(ie, cc)]);
      }
#pragma unroll
      for (int mf = 0; mf < 2; ++mf)
#pragma unroll
        for (int nf = 0; nf < 4; ++nf)
          acc[mf][4 + nf] = __builtin_amdgcn_mfma_f32_16x16x32_bf16(afr[mf], bfr[nf], acc[mf][4 + nf], 0, 0, 0);
    }
    __syncthreads();  // all waves done reading X before it is overwritten

    if (layer < 2) {
      // bias + relu -> bf16 back into X (D frag: pos = l16 col, o = g16*4+v)
#pragma unroll
      for (int mf = 0; mf < 2; ++mf) {
        int o0 = ow + mf * 16 + g16 * 4;
        f32x4 bv = *(const f32x4*)(bias + o0);
#pragma unroll
        for (int nf = 0; nf < 8; ++nf) {
          int pos = nf * 16 + l16;     // 0..127 covers both rows
          u16x4 pk;
#pragma unroll
          for (int v = 0; v < 4; ++v)
            pk[v] = f2bf(fmaxf(acc[mf][nf][v] + bv[v], 0.f));
          *(u16x4*)&X[xaddr(pos, o0)] = pk;
        }
      }
      __syncthreads();
    } else {
      // final: bias+relu -> fp32 bounce over FULL 64KB (X dead) -> f32x4
      // stores. One round per row; all 8 waves write their 32-o slice.
#pragma unroll
      for (int rr = 0; rr < 2; ++rr) {
#pragma unroll
        for (int mf = 0; mf < 2; ++mf) {
          int oh0 = ow + mf * 16 + g16 * 4;      // 0..255
          f32x4 bv = *(const f32x4*)(bias + oh0);
#pragma unroll
          for (int nq = 0; nq < 4; ++nq) {
            int pos = nq * 16 + l16;             // within-row position
#pragma unroll
            for (int v = 0; v < 4; ++v) {
              int oh = oh0 + v;
              bounce[oh * 64 + (pos ^ ((oh & 7) << 2))] =
                  fmaxf(acc[mf][rr * 4 + nq][v] + bv[v], 0.f);
            }
          }
        }
        __syncthreads();
        // read back along pos, coalesced f32x4 global stores (64KB = 8/thread)
        int bq = b0 + 16 * rr;
#pragma unroll
        for (int q = 0; q < 8; ++q) {
          int u = q * 512 + tid;                 // 0..4095
          int oh = u >> 4;                       // 0..255
          int pos4 = (u & 15) << 2;
          f32x4 vv = *(const f32x4*)&bounce[oh * 64 + (pos4 ^ ((oh & 7) << 2))];
          *(f32x4*)&out[(((bq * 256 + oh) * 63) + dd) * 64 + pos4] = vv;
        }
        if (rr == 0) __syncthreads();            // row0 reads done before row1 writes
      }
    }
  }
}

extern "C" void kernel_launch(void* const* d_in, const int* in_sizes, int n_in,
                              void* d_out, int out_size, void* d_ws, size_t ws_size,
                              hipStream_t stream) {
  const float* x  = (const float*)d_in[0];
  const float* xc = (const float*)d_in[1];
  const float* W1 = (const float*)d_in[2];
  const float* b1 = (const float*)d_in[3];
  const float* W2 = (const float*)d_in[4];
  const float* b2 = (const float*)d_in[5];
  const float* W3 = (const float*)d_in[6];
  const float* b3 = (const float*)d_in[7];
  float* out = (float*)d_out;
  unsigned short* wb = (unsigned short*)d_ws;  // 3 x 256 x 256 bf16 = 384 KB

  wconv_kernel<<<64, 256, 0, stream>>>(W1, W2, W3, wb);
  fused_kernel<<<1008, 512, 0, stream>>>(x, xc, wb, b1, b2, b3, out);
}